// Round 1
// baseline (536.113 us; speedup 1.0000x reference)
//
#include <hip/hip_runtime.h>

constexpr int DIM = 96;
constexpr int HW  = DIM * DIM;            // 9216
constexpr int DHW = DIM * DIM * DIM;      // 884736
constexpr int NC  = 64;
constexpr int NK  = 27;

constexpr int TZ = 4, TY = 8, TX = 32;    // block tile (z,y,x)
constexpr int LZ = TZ + 2, LY = TY + 2, LX = TX + 2;  // 6,10,34 halo tile
constexpr int LXP = 36;                   // padded row stride (multiple of 4 floats -> 16B)
constexpr int LDS_N = LZ * LY * LX;       // 2040 staged elements
constexpr int NSTG = (LDS_N + 255) / 256; // 8 per thread

__global__ __launch_bounds__(256, 3)
void wincorr_kernel(const float* __restrict__ fixed_,
                    const float* __restrict__ moving,
                    float* __restrict__ out)
{
    __shared__ __align__(16) float sm[LZ * LY * LXP];

    const int tid = threadIdx.x;
    const int tx = tid & 7;          // 8 x-chunks of 4
    const int ty = (tid >> 3) & 7;   // 8 y
    const int tz = tid >> 6;         // 4 z  (== wave id)
    const int bx0 = blockIdx.x * TX;
    const int by0 = blockIdx.y * TY;
    const int bz0 = blockIdx.z * TZ;

    // Precompute staging offsets (channel-invariant). Edge clamp here.
    int g_off[NSTG], s_off[NSTG];
#pragma unroll
    for (int i = 0; i < NSTG; ++i) {
        int t = tid + i * 256;
        if (t < LDS_N) {
            int lz = t / (LY * LX);
            int r  = t % (LY * LX);
            int ly = r / LX;
            int lx = r % LX;
            int gz = min(max(bz0 - 1 + lz, 0), DIM - 1);
            int gy = min(max(by0 - 1 + ly, 0), DIM - 1);
            int gx = min(max(bx0 - 1 + lx, 0), DIM - 1);
            g_off[i] = gz * HW + gy * DIM + gx;
            s_off[i] = (lz * LY + ly) * LXP + lx;
        } else {
            g_off[i] = 0; s_off[i] = -1;
        }
    }

    const int z = bz0 + tz, y = by0 + ty, x0 = bx0 + 4 * tx;
    const int foff = z * HW + y * DIM + x0;

    float acc[NK][4];
#pragma unroll
    for (int k = 0; k < NK; ++k)
#pragma unroll
        for (int j = 0; j < 4; ++j) acc[k][j] = 0.f;

    // Prefetch channel 0
    float pre[NSTG];
#pragma unroll
    for (int i = 0; i < NSTG; ++i)
        if (s_off[i] >= 0) pre[i] = moving[g_off[i]];
    float4 pf = *(const float4*)(fixed_ + foff);

    for (int c = 0; c < NC; ++c) {
        if (c) __syncthreads();                  // previous reads done
#pragma unroll
        for (int i = 0; i < NSTG; ++i)
            if (s_off[i] >= 0) sm[s_off[i]] = pre[i];
        const float4 fv = pf;
        __syncthreads();

        if (c + 1 < NC) {                        // prefetch next channel during compute
            const float* mc = moving + (c + 1) * DHW;
#pragma unroll
            for (int i = 0; i < NSTG; ++i)
                if (s_off[i] >= 0) pre[i] = mc[g_off[i]];
            pf = *(const float4*)(fixed_ + (c + 1) * DHW + foff);
        }

#pragma unroll
        for (int dz = 0; dz < 3; ++dz)
#pragma unroll
        for (int dy = 0; dy < 3; ++dy) {
            const float* row = &sm[((tz + dz) * LY + (ty + dy)) * LXP + 4 * tx];
            const float4 w0 = *(const float4*)row;        // 16B aligned
            const float2 w1 = *(const float2*)(row + 4);  // 8B aligned
            const float w[6] = {w0.x, w0.y, w0.z, w0.w, w1.x, w1.y};
            const int kb = (dz * 3 + dy) * 3;
#pragma unroll
            for (int dx = 0; dx < 3; ++dx) {
                acc[kb + dx][0] += fv.x * w[dx + 0];
                acc[kb + dx][1] += fv.y * w[dx + 1];
                acc[kb + dx][2] += fv.z * w[dx + 2];
                acc[kb + dx][3] += fv.w * w[dx + 3];
            }
        }
    }

    // Epilogue: scale by 64^-0.5 = 0.125 exactly, coalesced float4 stores
#pragma unroll
    for (int k = 0; k < NK; ++k) {
        float4 o;
        o.x = acc[k][0] * 0.125f;
        o.y = acc[k][1] * 0.125f;
        o.z = acc[k][2] * 0.125f;
        o.w = acc[k][3] * 0.125f;
        *(float4*)(out + k * DHW + foff) = o;
    }
}

extern "C" void kernel_launch(void* const* d_in, const int* in_sizes, int n_in,
                              void* d_out, int out_size, void* d_ws, size_t ws_size,
                              hipStream_t stream) {
    const float* fixed_  = (const float*)d_in[0];
    const float* moving  = (const float*)d_in[1];
    float* out = (float*)d_out;
    dim3 grid(DIM / TX, DIM / TY, DIM / TZ);   // 3 x 12 x 24 = 864 blocks
    dim3 block(256);
    wincorr_kernel<<<grid, block, 0, stream>>>(fixed_, moving, out);
}